// Round 1
// baseline (610.775 us; speedup 1.0000x reference)
//
#include <hip/hip_runtime.h>

typedef __attribute__((ext_vector_type(4))) float f32x4;
typedef __attribute__((ext_vector_type(8))) short bf16x8;
typedef __attribute__((ext_vector_type(4))) short bf16x4;
typedef unsigned short u16;

#define MFMA16(a, b, c) __builtin_amdgcn_mfma_f32_16x16x32_bf16((a), (b), (c), 0, 0, 0)

#define T_SEQ 2048
#define DMODEL 2048
#define NHEADS 16
#define HDIM 128
#define WINDOW 256
#define MROWS 4096  // B*T

__device__ __forceinline__ u16 f2bf(float f) {
  union { float f; unsigned u; } v; v.f = f;
  return (u16)((v.u + 0x7FFFu + ((v.u >> 16) & 1u)) >> 16);
}

// ---------------------------------------------------------------------------
// GEMM: C[M,N] = A[M,K] @ B[N,K]^T   (nn.Linear with row-major weight)
// A: f32 (ABF16=false) or bf16-as-u16 (ABF16=true). B: always f32.
// C: f32 (CF32=true) or bf16 (CF32=false).
// 128x128 tile, BK=32, 256 threads = 4 waves in 2x2, each wave 64x64 (4x4 frags).
// ---------------------------------------------------------------------------
#define BM 128
#define BN 128
#define BK 32
#define LDT 40  // padded LDS row length (bf16 elems): 80B rows -> bank-balanced

template <bool ABF16, bool CF32>
__global__ __launch_bounds__(256) void gemm_bt(const void* __restrict__ Ap,
                                               const float* __restrict__ Bw,
                                               void* __restrict__ Cp,
                                               int M, int N, int K) {
  __shared__ u16 As[BM][LDT];
  __shared__ u16 Bs[BN][LDT];

  const int tid = threadIdx.x;
  const int wave = tid >> 6, lane = tid & 63;
  const int wm = (wave >> 1) * 64, wn = (wave & 1) * 64;
  const int fr = lane & 15;           // fragment row (A) / col (B,C)
  const int ko = (lane >> 4) * 8;     // k-octet offset
  const int m0 = blockIdx.y * BM, n0 = blockIdx.x * BN;

  const int arow = tid >> 3;          // 0..31
  const int acol = (tid & 7) * 4;     // float4 column within BK

  f32x4 acc[4][4];
#pragma unroll
  for (int i = 0; i < 4; ++i)
#pragma unroll
    for (int j = 0; j < 4; ++j) acc[i][j] = (f32x4){0.f, 0.f, 0.f, 0.f};

  for (int k0 = 0; k0 < K; k0 += BK) {
#pragma unroll
    for (int it = 0; it < 4; ++it) {
      const int r = arow + it * 32;
      // ---- stage A tile (convert to bf16 if needed) ----
      if (ABF16) {
        const u16* A = (const u16*)Ap;
        bf16x4 v = *(const bf16x4*)&A[(size_t)(m0 + r) * K + k0 + acol];
        *(bf16x4*)&As[r][acol] = v;
      } else {
        const float* A = (const float*)Ap;
        f32x4 v = *(const f32x4*)&A[(size_t)(m0 + r) * K + k0 + acol];
        bf16x4 o;
#pragma unroll
        for (int j = 0; j < 4; ++j) o[j] = (short)f2bf(v[j]);
        *(bf16x4*)&As[r][acol] = o;
      }
      // ---- stage B tile (always f32 -> bf16) ----
      {
        f32x4 v = *(const f32x4*)&Bw[(size_t)(n0 + r) * K + k0 + acol];
        bf16x4 o;
#pragma unroll
        for (int j = 0; j < 4; ++j) o[j] = (short)f2bf(v[j]);
        *(bf16x4*)&Bs[r][acol] = o;
      }
    }
    __syncthreads();

    bf16x8 af[4], bf[4];
#pragma unroll
    for (int i = 0; i < 4; ++i) af[i] = *(const bf16x8*)&As[wm + i * 16 + fr][ko];
#pragma unroll
    for (int i = 0; i < 4; ++i) bf[i] = *(const bf16x8*)&Bs[wn + i * 16 + fr][ko];
#pragma unroll
    for (int mi = 0; mi < 4; ++mi)
#pragma unroll
      for (int ni = 0; ni < 4; ++ni)
        acc[mi][ni] = MFMA16(af[mi], bf[ni], acc[mi][ni]);
    __syncthreads();
  }

  // epilogue: C row = (lane>>4)*4 + reg, col = lane&15
#pragma unroll
  for (int mi = 0; mi < 4; ++mi)
#pragma unroll
    for (int ni = 0; ni < 4; ++ni) {
      const int r0 = m0 + wm + mi * 16 + (lane >> 4) * 4;
      const int c = n0 + wn + ni * 16 + fr;
#pragma unroll
      for (int r = 0; r < 4; ++r) {
        const float val = acc[mi][ni][r];
        if (CF32)
          ((float*)Cp)[(size_t)(r0 + r) * N + c] = val;
        else
          ((u16*)Cp)[(size_t)(r0 + r) * N + c] = f2bf(val);
      }
    }
}

// ---------------------------------------------------------------------------
// Striped flash attention. Grid: (qt=T/64, h=16, b=2). 256 threads = 4 waves,
// each wave owns 16 q-rows. KV tile = 64. Even heads causal, odd heads banded.
// q/k/v/out are bf16 [B*T][2048], head h at cols h*128..h*128+127.
// ---------------------------------------------------------------------------
#define QB 64
#define KVB 64
#define LDK 136  // K tile padded row (bf16)
#define LDV 72   // V^T tile padded row
#define LDP 72   // P tile padded row

__global__ __launch_bounds__(256) void attn_kernel(const u16* __restrict__ qp,
                                                   const u16* __restrict__ kp,
                                                   const u16* __restrict__ vp,
                                                   u16* __restrict__ op) {
  __shared__ u16 Ks[KVB][LDK];     // 17408 B
  __shared__ u16 Vt[HDIM][LDV];    // 18432 B  (V transposed: Vt[d][kv])
  __shared__ u16 Ps[4][16][LDP];   // 9216 B   (per-wave P tile)

  const int qt = blockIdx.x, h = blockIdx.y, b = blockIdx.z;
  const int tid = threadIdx.x, wave = tid >> 6, lane = tid & 63;
  const int fr = lane & 15, ko = (lane >> 4) * 8;
  const bool isglobal = (h & 1) == 0;
  const int q0 = qt * QB;
  const size_t base = (size_t)b * T_SEQ * DMODEL + (size_t)h * HDIM;
  const float sc = 0.08838834764831845f;  // 1/sqrt(128)

  // Q fragments for this wave's 16 rows (row = lane&15), 4 d-slices of 32
  bf16x8 qf[4];
  {
    const int qrow = q0 + wave * 16 + fr;
#pragma unroll
    for (int ds = 0; ds < 4; ++ds)
      qf[ds] = *(const bf16x8*)&qp[base + (size_t)qrow * DMODEL + ds * 32 + ko];
  }

  float mrun[4], lrun[4];
#pragma unroll
  for (int r = 0; r < 4; ++r) { mrun[r] = -1e30f; lrun[r] = 0.f; }
  f32x4 o[8];
#pragma unroll
  for (int dt = 0; dt < 8; ++dt) o[dt] = (f32x4){0.f, 0.f, 0.f, 0.f};

  int kt0 = 0;
  if (!isglobal) {
    const int lo = q0 - (WINDOW - 1);
    if (lo > 0) kt0 = lo >> 6;
  }

  for (int kt = kt0; kt <= qt; ++kt) {
    __syncthreads();
    // ---- stage K tile [64][128] and V^T tile [128][64] ----
    {
      const int r = tid >> 4;          // 0..15
      const int c = (tid & 15) * 8;    // octet column
#pragma unroll
      for (int it = 0; it < 4; ++it) {
        const int row = r + it * 16;
        const size_t g = base + (size_t)(kt * KVB + row) * DMODEL + c;
        bf16x8 kv8 = *(const bf16x8*)&kp[g];
        *(bf16x8*)&Ks[row][c] = kv8;
        bf16x8 vv8 = *(const bf16x8*)&vp[g];
#pragma unroll
        for (int j = 0; j < 8; ++j) Vt[c + j][row] = (u16)vv8[j];
      }
    }
    __syncthreads();

    // ---- S = Q K^T : 4 16x16 tiles over kv ----
    f32x4 s[4];
#pragma unroll
    for (int kk = 0; kk < 4; ++kk) {
      f32x4 a = (f32x4){0.f, 0.f, 0.f, 0.f};
#pragma unroll
      for (int ds = 0; ds < 4; ++ds) {
        bf16x8 kf = *(const bf16x8*)&Ks[kk * 16 + fr][ds * 32 + ko];
        a = MFMA16(qf[ds], kf, a);
      }
      s[kk] = a;
    }

    // ---- masked online softmax (rows live across 16 lanes) ----
    const int rbase = q0 + wave * 16 + (lane >> 4) * 4;
#pragma unroll
    for (int r = 0; r < 4; ++r) {
      const int qg = rbase + r;
      float sv[4];
      bool al[4];
      float pmax = -1e30f;
#pragma unroll
      for (int kk = 0; kk < 4; ++kk) {
        const int cg = kt * KVB + kk * 16 + fr;
        const bool allowed = (cg <= qg) && (isglobal || cg >= qg - (WINDOW - 1));
        al[kk] = allowed;
        sv[kk] = s[kk][r];
        pmax = fmaxf(pmax, allowed ? sv[kk] : -1e30f);
      }
#pragma unroll
      for (int msk = 1; msk < 16; msk <<= 1)
        pmax = fmaxf(pmax, __shfl_xor(pmax, msk, 64));
      const float nm = fmaxf(mrun[r], pmax);
      const float fac = __expf((mrun[r] - nm) * sc);
      float rs = 0.f;
      u16 pb[4];
#pragma unroll
      for (int kk = 0; kk < 4; ++kk) {
        const float p = al[kk] ? __expf((sv[kk] - nm) * sc) : 0.f;
        rs += p;
        pb[kk] = f2bf(p);
      }
#pragma unroll
      for (int msk = 1; msk < 16; msk <<= 1) rs += __shfl_xor(rs, msk, 64);
      mrun[r] = nm;
      lrun[r] = lrun[r] * fac + rs;
#pragma unroll
      for (int dt = 0; dt < 8; ++dt) o[dt][r] *= fac;
      const int wrow = (lane >> 4) * 4 + r;
#pragma unroll
      for (int kk = 0; kk < 4; ++kk) Ps[wave][wrow][kk * 16 + fr] = pb[kk];
    }

    // ---- O += P V  (P from per-wave LDS tile; V^T gives contiguous frags) ----
    bf16x8 pf0 = *(const bf16x8*)&Ps[wave][fr][ko];
    bf16x8 pf1 = *(const bf16x8*)&Ps[wave][fr][32 + ko];
#pragma unroll
    for (int dt = 0; dt < 8; ++dt) {
      bf16x8 vf0 = *(const bf16x8*)&Vt[dt * 16 + fr][ko];
      bf16x8 vf1 = *(const bf16x8*)&Vt[dt * 16 + fr][32 + ko];
      o[dt] = MFMA16(pf0, vf0, o[dt]);
      o[dt] = MFMA16(pf1, vf1, o[dt]);
    }
  }

  // ---- epilogue: divide by softmax denom, store bf16 ----
#pragma unroll
  for (int r = 0; r < 4; ++r) {
    const float inv = 1.0f / lrun[r];
    const int qg = q0 + wave * 16 + (lane >> 4) * 4 + r;
#pragma unroll
    for (int dt = 0; dt < 8; ++dt)
      op[base + (size_t)qg * DMODEL + dt * 16 + fr] = f2bf(o[dt][r] * inv);
  }
}

// ---------------------------------------------------------------------------
extern "C" void kernel_launch(void* const* d_in, const int* in_sizes, int n_in,
                              void* d_out, int out_size, void* d_ws, size_t ws_size,
                              hipStream_t stream) {
  (void)in_sizes; (void)n_in; (void)out_size; (void)ws_size;
  const float* x  = (const float*)d_in[0];
  const float* Wq = (const float*)d_in[1];
  const float* Wk = (const float*)d_in[2];
  const float* Wv = (const float*)d_in[3];
  const float* Wo = (const float*)d_in[4];
  float* out = (float*)d_out;

  const size_t NEL = (size_t)MROWS * DMODEL;
  u16* qb = (u16*)d_ws;
  u16* kb = qb + NEL;
  u16* vb = kb + NEL;
  u16* ab = vb + NEL;

  dim3 blk(256);
  dim3 gg(DMODEL / BN, MROWS / BM);  // (16, 32)

  gemm_bt<false, false><<<gg, blk, 0, stream>>>((const void*)x, Wq, (void*)qb, MROWS, DMODEL, DMODEL);
  gemm_bt<false, false><<<gg, blk, 0, stream>>>((const void*)x, Wk, (void*)kb, MROWS, DMODEL, DMODEL);
  gemm_bt<false, false><<<gg, blk, 0, stream>>>((const void*)x, Wv, (void*)vb, MROWS, DMODEL, DMODEL);

  attn_kernel<<<dim3(T_SEQ / QB, NHEADS, 2), blk, 0, stream>>>(qb, kb, vb, ab);

  gemm_bt<true, true><<<gg, blk, 0, stream>>>((const void*)ab, Wo, (void*)out, MROWS, DMODEL, DMODEL);
}

// Round 2
// 378.754 us; speedup vs baseline: 1.6126x; 1.6126x over previous
//
#include <hip/hip_runtime.h>

typedef __attribute__((ext_vector_type(4))) float f32x4;
typedef __attribute__((ext_vector_type(8))) short bf16x8;
typedef __attribute__((ext_vector_type(4))) unsigned short u16x4;
typedef unsigned short u16;

#define MFMA16(a, b, c) __builtin_amdgcn_mfma_f32_16x16x32_bf16((a), (b), (c), 0, 0, 0)

#define T_SEQ 2048
#define DMODEL 2048
#define NHEADS 16
#define HDIM 128
#define WINDOW 256
#define MROWS 4096  // B*T

__device__ __forceinline__ u16 f2bf(float f) {
  union { float f; unsigned u; } v; v.f = f;
  return (u16)((v.u + 0x7FFFu + ((v.u >> 16) & 1u)) >> 16);
}

__device__ __forceinline__ void gl_lds16(const u16* g, u16* l) {
  __builtin_amdgcn_global_load_lds((const __attribute__((address_space(1))) void*)(g),
                                   (__attribute__((address_space(3))) void*)(l), 16, 0, 0);
}

// ---------------------------------------------------------------------------
// Convert x, Wq, Wk, Wv, Wo (f32) -> contiguous bf16 region at dst.
// Layout: [xb NX][wqb NW][wkb NW][wvb NW][wob NW]
// ---------------------------------------------------------------------------
__global__ __launch_bounds__(256) void convert_all(const float* __restrict__ x,
                                                   const float* __restrict__ wq,
                                                   const float* __restrict__ wk,
                                                   const float* __restrict__ wv,
                                                   const float* __restrict__ wo,
                                                   u16* __restrict__ dst) {
  const size_t NX = (size_t)MROWS * DMODEL;
  const size_t NW = (size_t)DMODEL * DMODEL;
  const size_t chunks = (NX + 4 * NW) / 8;
  for (size_t ci = (size_t)blockIdx.x * 256 + threadIdx.x; ci < chunks;
       ci += (size_t)gridDim.x * 256) {
    const size_t off = ci * 8;
    const float* src;
    size_t so;
    if (off < NX) { src = x; so = off; }
    else {
      size_t rem = off - NX;
      if (rem < NW) { src = wq; so = rem; }
      else if (rem < 2 * NW) { src = wk; so = rem - NW; }
      else if (rem < 3 * NW) { src = wv; so = rem - 2 * NW; }
      else { src = wo; so = rem - 3 * NW; }
    }
    f32x4 a = *(const f32x4*)&src[so];
    f32x4 b = *(const f32x4*)&src[so + 4];
    bf16x8 o;
#pragma unroll
    for (int j = 0; j < 4; ++j) { o[j] = (short)f2bf(a[j]); o[j + 4] = (short)f2bf(b[j]); }
    *(bf16x8*)&dst[off] = o;
  }
}

// ---------------------------------------------------------------------------
// m97-structure GEMM: C = A[M,K](bf16) @ W[N,K]^T(bf16). 128x128 tile, BK=32,
// 4 waves 2x2, global_load_lds width-16 staging, linear LDS.
// EPI=0: QKV fused (N=6144): cols<4096 -> qk bf16 (stride 4096);
//        cols>=4096 -> V written TRANSPOSED to vt[(b*16+h)*128+d][t] bf16.
// EPI=1: OUT: f32 C, stride 2048.
// ---------------------------------------------------------------------------
#define BM 128
#define BN 128
#define BK 32

template <int EPI>
__global__ __launch_bounds__(256) void gemm_fast(const u16* __restrict__ A,
                                                 const u16* __restrict__ W0,
                                                 const u16* __restrict__ W1,
                                                 const u16* __restrict__ W2,
                                                 u16* __restrict__ qk,
                                                 u16* __restrict__ vt,
                                                 float* __restrict__ outf,
                                                 int K) {
  __shared__ u16 As[BM * BK];
  __shared__ u16 Bs[BN * BK];
  const int tid = threadIdx.x, wave = tid >> 6, lane = tid & 63;
  const int fr = lane & 15, ko = (lane >> 4) * 8;
  const int wm = (wave >> 1) * 64, wn = (wave & 1) * 64;
  const int m0 = blockIdx.y * BM, n0 = blockIdx.x * BN;

  const u16* Bw;
  int nloc;
  if (EPI == 0) {
    const int wsel = n0 >> 11;
    Bw = (wsel == 0) ? W0 : ((wsel == 1) ? W1 : W2);
    nloc = n0 & 2047;
  } else {
    Bw = W0;
    nloc = n0;
  }

  const int srow = tid >> 2;        // slot row for issue 0 (slots 0..255)
  const int scol = (tid & 3) * 8;   // elem col

  f32x4 acc[4][4];
#pragma unroll
  for (int i = 0; i < 4; ++i)
#pragma unroll
    for (int j = 0; j < 4; ++j) acc[i][j] = (f32x4){0.f, 0.f, 0.f, 0.f};

  for (int k0 = 0; k0 < K; k0 += BK) {
#pragma unroll
    for (int i = 0; i < 2; ++i) {
      const int row = srow + i * 64;  // slot s = i*256+tid; row = s>>2
      gl_lds16(&A[(size_t)(m0 + row) * K + k0 + scol], &As[(i * 256 + wave * 64) * 8]);
      gl_lds16(&Bw[(size_t)(nloc + row) * K + k0 + scol], &Bs[(i * 256 + wave * 64) * 8]);
    }
    __syncthreads();
    bf16x8 af[4], bfr[4];
#pragma unroll
    for (int i = 0; i < 4; ++i) af[i] = *(const bf16x8*)&As[(wm + i * 16 + fr) * BK + ko];
#pragma unroll
    for (int i = 0; i < 4; ++i) bfr[i] = *(const bf16x8*)&Bs[(wn + i * 16 + fr) * BK + ko];
#pragma unroll
    for (int mi = 0; mi < 4; ++mi)
#pragma unroll
      for (int ni = 0; ni < 4; ++ni)
        acc[mi][ni] = MFMA16(af[mi], bfr[ni], acc[mi][ni]);
    __syncthreads();
  }

#pragma unroll
  for (int mi = 0; mi < 4; ++mi)
#pragma unroll
    for (int ni = 0; ni < 4; ++ni) {
      const int row0 = m0 + wm + mi * 16 + (lane >> 4) * 4;
      const int c = n0 + wn + ni * 16 + fr;
      if (EPI == 1) {
#pragma unroll
        for (int r = 0; r < 4; ++r)
          outf[(size_t)(row0 + r) * DMODEL + c] = acc[mi][ni][r];
      } else {
        if (c < 2 * DMODEL) {
#pragma unroll
          for (int r = 0; r < 4; ++r)
            qk[(size_t)(row0 + r) * (2 * DMODEL) + c] = f2bf(acc[mi][ni][r]);
        } else {
          const int cc = c - 2 * DMODEL;
          const int hh = cc >> 7, d = cc & 127;
          const int bb = row0 >> 11, tl = row0 & 2047;
          u16x4 w4;
#pragma unroll
          for (int r = 0; r < 4; ++r) w4[r] = f2bf(acc[mi][ni][r]);
          *(u16x4*)&vt[((size_t)(bb * NHEADS + hh) * HDIM + d) * T_SEQ + tl] = w4;
        }
      }
    }
}

// ---------------------------------------------------------------------------
// Striped flash attention. Grid (32,16,2), 256 thr = 4 waves x 16 q-rows.
// qk: [4096][4096] bf16 (q cols 0..2047, k cols 2048..4095).
// vt: [b*16+h][128 d][2048 t] bf16 (V pre-transposed by GEMM epilogue).
// op: [4096][2048] bf16.
// ---------------------------------------------------------------------------
#define QB 64
#define KVB 64
#define LDK 136
#define LDV 72
#define LDP 72

__global__ __launch_bounds__(256) void attn_kernel(const u16* __restrict__ qk,
                                                   const u16* __restrict__ vt,
                                                   u16* __restrict__ op) {
  __shared__ u16 Ks[KVB][LDK];     // 17408 B
  __shared__ u16 Vs[HDIM][LDV];    // 18432 B (V^T: Vs[d][kv])
  __shared__ u16 Ps[4][16][LDP];   // 9216 B

  const int bx = blockIdx.x, h = blockIdx.y, b = blockIdx.z;
  const int qt = (T_SEQ / QB - 1) - bx;  // heavy tiles dispatched first
  const int tid = threadIdx.x, wave = tid >> 6, lane = tid & 63;
  const int fr = lane & 15, ko = (lane >> 4) * 8;
  const bool isglobal = (h & 1) == 0;
  const int q0 = qt * QB;
  const size_t baseq = (size_t)b * T_SEQ * (2 * DMODEL) + (size_t)h * HDIM;
  const size_t basek = baseq + DMODEL;
  const size_t basev = (size_t)(b * NHEADS + h) * HDIM * T_SEQ;
  const size_t baseo = (size_t)b * T_SEQ * DMODEL + (size_t)h * HDIM;
  const float sc = 0.08838834764831845f;  // 1/sqrt(128)

  bf16x8 qf[4];
  {
    const int qrow = q0 + wave * 16 + fr;
#pragma unroll
    for (int ds = 0; ds < 4; ++ds)
      qf[ds] = *(const bf16x8*)&qk[baseq + (size_t)qrow * (2 * DMODEL) + ds * 32 + ko];
  }

  float mrun[4], lrun[4];
#pragma unroll
  for (int r = 0; r < 4; ++r) { mrun[r] = -1e30f; lrun[r] = 0.f; }
  f32x4 o[8];
#pragma unroll
  for (int dt = 0; dt < 8; ++dt) o[dt] = (f32x4){0.f, 0.f, 0.f, 0.f};

  int kt0 = 0;
  if (!isglobal) {
    const int lo_ = q0 - (WINDOW - 1);
    if (lo_ > 0) kt0 = lo_ >> 6;
  }

  const int kr = tid >> 4;          // 0..15 (K stage)
  const int kc = (tid & 15) * 8;
  const int vr = tid >> 3;          // 0..31 (V stage)
  const int vc = (tid & 7) * 8;

  bf16x8 kreg[4], vreg[4];

#define LOADTILE(KT)                                                                      \
  {                                                                                       \
    _Pragma("unroll") for (int it = 0; it < 4; ++it) {                                    \
      kreg[it] = *(const bf16x8*)&qk[basek + (size_t)((KT) * KVB + kr + it * 16) * (2 * DMODEL) + kc]; \
      vreg[it] = *(const bf16x8*)&vt[basev + (size_t)(vr + it * 32) * T_SEQ + (KT) * KVB + vc];        \
    }                                                                                     \
  }
#define WRITETILE()                                                                       \
  {                                                                                       \
    _Pragma("unroll") for (int it = 0; it < 4; ++it) {                                    \
      *(bf16x8*)&Ks[kr + it * 16][kc] = kreg[it];                                         \
      *(bf16x8*)&Vs[vr + it * 32][vc] = vreg[it];                                         \
    }                                                                                     \
  }

  LOADTILE(kt0);
  WRITETILE();
  __syncthreads();

  for (int kt = kt0; kt <= qt; ++kt) {
    const bool more = kt < qt;
    if (more) LOADTILE(kt + 1);  // T14: issue next tile's loads before compute

    // ---- S = Q K^T ----
    f32x4 s[4];
#pragma unroll
    for (int kk = 0; kk < 4; ++kk) {
      f32x4 a = (f32x4){0.f, 0.f, 0.f, 0.f};
#pragma unroll
      for (int ds = 0; ds < 4; ++ds) {
        bf16x8 kf = *(const bf16x8*)&Ks[kk * 16 + fr][ds * 32 + ko];
        a = MFMA16(qf[ds], kf, a);
      }
      s[kk] = a;
    }

    // ---- masked online softmax ----
    const int rbase = q0 + wave * 16 + (lane >> 4) * 4;
#pragma unroll
    for (int r = 0; r < 4; ++r) {
      const int qg = rbase + r;
      float sv[4];
      bool al[4];
      float pmax = -1e30f;
#pragma unroll
      for (int kk = 0; kk < 4; ++kk) {
        const int cg = kt * KVB + kk * 16 + fr;
        const bool allowed = (cg <= qg) && (isglobal || cg >= qg - (WINDOW - 1));
        al[kk] = allowed;
        sv[kk] = s[kk][r];
        pmax = fmaxf(pmax, allowed ? sv[kk] : -1e30f);
      }
#pragma unroll
      for (int msk = 1; msk < 16; msk <<= 1)
        pmax = fmaxf(pmax, __shfl_xor(pmax, msk, 64));
      const float nm = fmaxf(mrun[r], pmax);
      const float fac = __expf((mrun[r] - nm) * sc);
      float rs = 0.f;
      u16 pb[4];
#pragma unroll
      for (int kk = 0; kk < 4; ++kk) {
        const float p = al[kk] ? __expf((sv[kk] - nm) * sc) : 0.f;
        rs += p;
        pb[kk] = f2bf(p);
      }
#pragma unroll
      for (int msk = 1; msk < 16; msk <<= 1) rs += __shfl_xor(rs, msk, 64);
      mrun[r] = nm;
      lrun[r] = lrun[r] * fac + rs;
#pragma unroll
      for (int dt = 0; dt < 8; ++dt) o[dt][r] *= fac;
      const int wrow = (lane >> 4) * 4 + r;
#pragma unroll
      for (int kk = 0; kk < 4; ++kk) Ps[wave][wrow][kk * 16 + fr] = pb[kk];
    }

    // ---- O += P V ----
    bf16x8 pf0 = *(const bf16x8*)&Ps[wave][fr][ko];
    bf16x8 pf1 = *(const bf16x8*)&Ps[wave][fr][32 + ko];
#pragma unroll
    for (int dt = 0; dt < 8; ++dt) {
      bf16x8 vf0 = *(const bf16x8*)&Vs[dt * 16 + fr][ko];
      bf16x8 vf1 = *(const bf16x8*)&Vs[dt * 16 + fr][32 + ko];
      o[dt] = MFMA16(pf0, vf0, o[dt]);
      o[dt] = MFMA16(pf1, vf1, o[dt]);
    }

    __syncthreads();
    if (more) WRITETILE();
    __syncthreads();
  }

#pragma unroll
  for (int r = 0; r < 4; ++r) {
    const float inv = 1.0f / lrun[r];
    const int qg = q0 + wave * 16 + (lane >> 4) * 4 + r;
#pragma unroll
    for (int dt = 0; dt < 8; ++dt)
      op[baseo + (size_t)qg * DMODEL + dt * 16 + fr] = f2bf(o[dt][r] * inv);
  }
}

// ---------------------------------------------------------------------------
extern "C" void kernel_launch(void* const* d_in, const int* in_sizes, int n_in,
                              void* d_out, int out_size, void* d_ws, size_t ws_size,
                              hipStream_t stream) {
  (void)in_sizes; (void)n_in; (void)out_size; (void)ws_size;
  const float* x  = (const float*)d_in[0];
  const float* Wq = (const float*)d_in[1];
  const float* Wk = (const float*)d_in[2];
  const float* Wv = (const float*)d_in[3];
  const float* Wo = (const float*)d_in[4];

  const size_t NX = (size_t)MROWS * DMODEL;   // 8,388,608
  const size_t NW = (size_t)DMODEL * DMODEL;  // 4,194,304
  u16* ws  = (u16*)d_ws;
  u16* xb  = ws;             // bf16 x; later reused as attention output (ab)
  u16* wqb = ws + NX;
  u16* wkb = wqb + NW;
  u16* wvb = wkb + NW;
  u16* wob = wvb + NW;
  u16* qkb = wob + NW;                        // [4096][4096]
  u16* vtb = qkb + (size_t)MROWS * 2 * DMODEL;  // [32][128][2048]
  // total: 100,663,296 bytes of d_ws

  convert_all<<<2048, 256, 0, stream>>>(x, Wq, Wk, Wv, Wo, ws);

  gemm_fast<0><<<dim3(3 * DMODEL / BN, MROWS / BM), 256, 0, stream>>>(
      xb, wqb, wkb, wvb, qkb, vtb, nullptr, DMODEL);

  attn_kernel<<<dim3(T_SEQ / QB, NHEADS, 2), 256, 0, stream>>>(qkb, vtb, xb);

  gemm_fast<1><<<dim3(DMODEL / BN, MROWS / BM), 256, 0, stream>>>(
      xb, wob, nullptr, nullptr, nullptr, nullptr, (float*)d_out, DMODEL);
}

// Round 3
// 322.325 us; speedup vs baseline: 1.8949x; 1.1751x over previous
//
#include <hip/hip_runtime.h>

typedef __attribute__((ext_vector_type(4))) float f32x4;
typedef __attribute__((ext_vector_type(8))) short bf16x8;
typedef __attribute__((ext_vector_type(4))) unsigned short u16x4;
typedef unsigned short u16;

#define MFMA16(a, b, c) __builtin_amdgcn_mfma_f32_16x16x32_bf16((a), (b), (c), 0, 0, 0)

#define T_SEQ 2048
#define DMODEL 2048
#define NHEADS 16
#define HDIM 128
#define WINDOW 256
#define MROWS 4096  // B*T
#define SC 0.08838834764831845f  // 1/sqrt(128)

__device__ __forceinline__ u16 f2bf(float f) {
  union { float f; unsigned u; } v; v.f = f;
  return (u16)((v.u + 0x7FFFu + ((v.u >> 16) & 1u)) >> 16);
}
__device__ __forceinline__ float bf2f(u16 u) {
  union { unsigned u; float f; } v; v.u = ((unsigned)u) << 16;
  return v.f;
}
__device__ __forceinline__ void gl_lds16(const u16* g, u16* l) {
  __builtin_amdgcn_global_load_lds((const __attribute__((address_space(1))) void*)(g),
                                   (__attribute__((address_space(3))) void*)(l), 16, 0, 0);
}

// ---------------------------------------------------------------------------
// Convert x, Wq, Wk, Wv, Wo (f32) -> contiguous bf16: [xb NX][wq][wk][wv][wo]
// ---------------------------------------------------------------------------
__global__ __launch_bounds__(256) void convert_all(const float* __restrict__ x,
                                                   const float* __restrict__ wq,
                                                   const float* __restrict__ wk,
                                                   const float* __restrict__ wv,
                                                   const float* __restrict__ wo,
                                                   u16* __restrict__ dst) {
  const size_t NX = (size_t)MROWS * DMODEL;
  const size_t NW = (size_t)DMODEL * DMODEL;
  const size_t chunks = (NX + 4 * NW) / 8;
  for (size_t ci = (size_t)blockIdx.x * 256 + threadIdx.x; ci < chunks;
       ci += (size_t)gridDim.x * 256) {
    const size_t off = ci * 8;
    const float* src;
    size_t so;
    if (off < NX) { src = x; so = off; }
    else {
      size_t rem = off - NX;
      if (rem < NW) { src = wq; so = rem; }
      else if (rem < 2 * NW) { src = wk; so = rem - NW; }
      else if (rem < 3 * NW) { src = wv; so = rem - 2 * NW; }
      else { src = wo; so = rem - 3 * NW; }
    }
    f32x4 a = *(const f32x4*)&src[so];
    f32x4 b = *(const f32x4*)&src[so + 4];
    bf16x8 o;
#pragma unroll
    for (int j = 0; j < 4; ++j) { o[j] = (short)f2bf(a[j]); o[j + 4] = (short)f2bf(b[j]); }
    *(bf16x8*)&dst[off] = o;
  }
}

// ---------------------------------------------------------------------------
// m97-structure GEMM + XCD swizzle. C = A[M,K](bf16) @ W[N,K]^T(bf16).
// EPI=0: QKV fused (N=6144): q,k -> qk buffer; V -> transposed vt buffer.
// EPI=1: OUT: f32 C.
// ---------------------------------------------------------------------------
#define BM 128
#define BN 128
#define BK 32

template <int EPI>
__global__ __launch_bounds__(256) void gemm_fast(const u16* __restrict__ A,
                                                 const u16* __restrict__ W0,
                                                 const u16* __restrict__ W1,
                                                 const u16* __restrict__ W2,
                                                 u16* __restrict__ qk,
                                                 u16* __restrict__ vt,
                                                 float* __restrict__ outf,
                                                 int K) {
  __shared__ u16 As[BM * BK];
  __shared__ u16 Bs[BN * BK];
  const int tid = threadIdx.x, wave = tid >> 6, lane = tid & 63;
  const int fr = lane & 15, ko = (lane >> 4) * 8;
  const int wm = (wave >> 1) * 64, wn = (wave & 1) * 64;

  // XCD-aware bijective swizzle (nwg % 8 == 0 for both uses)
  int flat = blockIdx.y * gridDim.x + blockIdx.x;
  const int nwg = gridDim.x * gridDim.y;
  const int cpx = nwg >> 3;
  flat = (flat & 7) * cpx + (flat >> 3);
  const int m0 = (flat / gridDim.x) * BM;
  const int n0 = (flat % gridDim.x) * BN;

  const u16* Bw;
  int nloc;
  if (EPI == 0) {
    const int wsel = n0 >> 11;
    Bw = (wsel == 0) ? W0 : ((wsel == 1) ? W1 : W2);
    nloc = n0 & 2047;
  } else {
    Bw = W0;
    nloc = n0;
  }

  const int srow = tid >> 2;
  const int scol = (tid & 3) * 8;

  f32x4 acc[4][4];
#pragma unroll
  for (int i = 0; i < 4; ++i)
#pragma unroll
    for (int j = 0; j < 4; ++j) acc[i][j] = (f32x4){0.f, 0.f, 0.f, 0.f};

  for (int k0 = 0; k0 < K; k0 += BK) {
#pragma unroll
    for (int i = 0; i < 2; ++i) {
      const int row = srow + i * 64;
      gl_lds16(&A[(size_t)(m0 + row) * K + k0 + scol], &As[(i * 256 + wave * 64) * 8]);
      gl_lds16(&Bw[(size_t)(nloc + row) * K + k0 + scol], &Bs[(i * 256 + wave * 64) * 8]);
    }
    __syncthreads();
    bf16x8 af[4], bfr[4];
#pragma unroll
    for (int i = 0; i < 4; ++i) af[i] = *(const bf16x8*)&As[(wm + i * 16 + fr) * BK + ko];
#pragma unroll
    for (int i = 0; i < 4; ++i) bfr[i] = *(const bf16x8*)&Bs[(wn + i * 16 + fr) * BK + ko];
#pragma unroll
    for (int mi = 0; mi < 4; ++mi)
#pragma unroll
      for (int ni = 0; ni < 4; ++ni)
        acc[mi][ni] = MFMA16(af[mi], bfr[ni], acc[mi][ni]);
    __syncthreads();
  }

#pragma unroll
  for (int mi = 0; mi < 4; ++mi)
#pragma unroll
    for (int ni = 0; ni < 4; ++ni) {
      const int row0 = m0 + wm + mi * 16 + (lane >> 4) * 4;
      const int c = n0 + wn + ni * 16 + fr;
      if (EPI == 1) {
#pragma unroll
        for (int r = 0; r < 4; ++r)
          outf[(size_t)(row0 + r) * DMODEL + c] = acc[mi][ni][r];
      } else {
        if (c < 2 * DMODEL) {
#pragma unroll
          for (int r = 0; r < 4; ++r)
            qk[(size_t)(row0 + r) * (2 * DMODEL) + c] = f2bf(acc[mi][ni][r]);
        } else {
          const int cc = c - 2 * DMODEL;
          const int hh = cc >> 7, d = cc & 127;
          const int bb = row0 >> 11, tl = row0 & 2047;
          u16x4 w4;
#pragma unroll
          for (int r = 0; r < 4; ++r) w4[r] = f2bf(acc[mi][ni][r]);
          *(u16x4*)&vt[((size_t)(bb * NHEADS + hh) * HDIM + d) * T_SEQ + tl] = w4;
        }
      }
    }
}

// ---------------------------------------------------------------------------
// Striped flash attention, swapped-QK softmax + split-KV for causal heads.
// Grid (48, 16, 2), 256 thr = 4 waves x 16 q-rows (QB=64), KV tile 64.
// Even h: bx -> c=47-bx; c<16: direct q-tile qt=c (tiles 0..qt);
//         c>=16: qt=16+((c-16)>>1), part=(c-16)&1 -> partial chunk.
// Odd h: bx<32: qt=31-bx, banded window, direct.
// Partials (bf16 O + f32 m,l) merged by merge_kernel.
// ---------------------------------------------------------------------------
#define QB 64
#define KVB 64
#define LDK 136
#define LDV 72
#define LDP 80

__global__ __launch_bounds__(256) void attn_kernel(const u16* __restrict__ qk,
                                                   const u16* __restrict__ vt,
                                                   u16* __restrict__ op,
                                                   u16* __restrict__ pO,
                                                   float* __restrict__ pm,
                                                   float* __restrict__ pl) {
  __shared__ u16 Ks[KVB][LDK];
  __shared__ u16 Vs[HDIM][LDV];
  __shared__ u16 Ps[4][16][LDP];

  const int bx = blockIdx.x, h = blockIdx.y, b = blockIdx.z;
  const bool isglobal = (h & 1) == 0;
  int qt, klo, khi, part = 0;
  bool partial = false;
  if (isglobal) {
    const int c = 47 - bx;
    if (c < 16) { qt = c; klo = 0; khi = qt; }
    else {
      qt = 16 + ((c - 16) >> 1);
      part = (c - 16) & 1;
      partial = true;
      if (part == 0) { klo = 0; khi = 15; } else { klo = 16; khi = qt; }
    }
  } else {
    if (bx >= 32) return;
    qt = 31 - bx;
    const int lo_ = qt * QB - (WINDOW - 1);
    klo = lo_ > 0 ? (lo_ >> 6) : 0;
    khi = qt;
  }

  const int tid = threadIdx.x, wave = tid >> 6, lane = tid & 63;
  const int fr = lane & 15, ko = (lane >> 4) * 8, g4 = (lane >> 4) * 4;
  const int q0 = qt * QB;
  const size_t baseq = (size_t)b * T_SEQ * (2 * DMODEL) + (size_t)h * HDIM;
  const size_t basek = baseq + DMODEL;
  const size_t basev = (size_t)(b * NHEADS + h) * HDIM * T_SEQ;
  const size_t baseo = (size_t)b * T_SEQ * DMODEL + (size_t)h * HDIM;

  // Q fragments: B-operand for swapped QK (row = lane&15 = q-row)
  bf16x8 qf[4];
  {
    const int qrow = q0 + wave * 16 + fr;
#pragma unroll
    for (int ds = 0; ds < 4; ++ds)
      qf[ds] = *(const bf16x8*)&qk[baseq + (size_t)qrow * (2 * DMODEL) + ds * 32 + ko];
  }

  float mrun = -1e30f, lrun = 0.f;
  f32x4 o[8];
#pragma unroll
  for (int dt = 0; dt < 8; ++dt) o[dt] = (f32x4){0.f, 0.f, 0.f, 0.f};

  const int kr = tid >> 4, kc = (tid & 15) * 8;
  const int vr = tid >> 3, vc = (tid & 7) * 8;
  bf16x8 kreg[4], vreg[4];

#define LOADTILE(KT)                                                                      \
  {                                                                                       \
    _Pragma("unroll") for (int it = 0; it < 4; ++it) {                                    \
      kreg[it] = *(const bf16x8*)&qk[basek + (size_t)((KT) * KVB + kr + it * 16) * (2 * DMODEL) + kc]; \
      vreg[it] = *(const bf16x8*)&vt[basev + (size_t)(vr + it * 32) * T_SEQ + (KT) * KVB + vc];        \
    }                                                                                     \
  }
#define WRITETILE()                                                                       \
  {                                                                                       \
    _Pragma("unroll") for (int it = 0; it < 4; ++it) {                                    \
      *(bf16x8*)&Ks[kr + it * 16][kc] = kreg[it];                                         \
      *(bf16x8*)&Vs[vr + it * 32][vc] = vreg[it];                                         \
    }                                                                                     \
  }

  LOADTILE(klo);
  WRITETILE();
  __syncthreads();

  const int qg = q0 + wave * 16 + fr;  // this lane's q-row (softmax owner)

  for (int kt = klo; kt <= khi; ++kt) {
    const bool more = kt < khi;
    if (more) LOADTILE(kt + 1);

    // ---- S = K Q^T (swapped): lane holds q=fr, kv = kk*16 + g4 + reg ----
    f32x4 s[4];
    __builtin_amdgcn_s_setprio(1);
#pragma unroll
    for (int kk = 0; kk < 4; ++kk) {
      f32x4 a = (f32x4){0.f, 0.f, 0.f, 0.f};
#pragma unroll
      for (int ds = 0; ds < 4; ++ds) {
        bf16x8 kf = *(const bf16x8*)&Ks[kk * 16 + fr][ds * 32 + ko];
        a = MFMA16(kf, qf[ds], a);
      }
      s[kk] = a;
    }
    __builtin_amdgcn_s_setprio(0);

    // ---- masked online softmax (each lane owns one q-row) ----
    float sv[16];
    float pmax = -1e30f;
#pragma unroll
    for (int kk = 0; kk < 4; ++kk)
#pragma unroll
      for (int reg = 0; reg < 4; ++reg) {
        const int cg = kt * KVB + kk * 16 + g4 + reg;
        const bool allowed = (cg <= qg) && (isglobal || cg >= qg - (WINDOW - 1));
        const float v = allowed ? s[kk][reg] : -1e30f;
        sv[kk * 4 + reg] = v;
        pmax = fmaxf(pmax, v);
      }
    pmax = fmaxf(pmax, __shfl_xor(pmax, 16, 64));
    pmax = fmaxf(pmax, __shfl_xor(pmax, 32, 64));
    const float nm = fmaxf(mrun, pmax);
    const float fac = __expf((mrun - nm) * SC);
    mrun = nm;
    float rs = 0.f;
    u16 pb[16];
#pragma unroll
    for (int i = 0; i < 16; ++i) {
      const float p = (sv[i] > -5e29f) ? __expf((sv[i] - nm) * SC) : 0.f;
      rs += p;
      pb[i] = f2bf(p);
    }
    rs += __shfl_xor(rs, 16, 64);
    rs += __shfl_xor(rs, 32, 64);
    lrun = lrun * fac + rs;

    // P -> per-wave LDS (vectorized 8B writes; row = q = fr)
#pragma unroll
    for (int kk = 0; kk < 4; ++kk) {
      u16x4 w;
      w[0] = pb[kk * 4]; w[1] = pb[kk * 4 + 1]; w[2] = pb[kk * 4 + 2]; w[3] = pb[kk * 4 + 3];
      *(u16x4*)&Ps[wave][fr][kk * 16 + g4] = w;
    }

    // rescale O (O rows = g4+reg; fetch fac from owner lanes)
    float ff[4];
#pragma unroll
    for (int r = 0; r < 4; ++r) ff[r] = __shfl(fac, g4 + r, 64);
#pragma unroll
    for (int dt = 0; dt < 8; ++dt)
#pragma unroll
      for (int r = 0; r < 4; ++r) o[dt][r] *= ff[r];

    // ---- O += P V ----
    bf16x8 pf0 = *(const bf16x8*)&Ps[wave][fr][ko];
    bf16x8 pf1 = *(const bf16x8*)&Ps[wave][fr][32 + ko];
    __builtin_amdgcn_s_setprio(1);
#pragma unroll
    for (int dt = 0; dt < 8; ++dt) {
      bf16x8 vf0 = *(const bf16x8*)&Vs[dt * 16 + fr][ko];
      bf16x8 vf1 = *(const bf16x8*)&Vs[dt * 16 + fr][32 + ko];
      o[dt] = MFMA16(pf0, vf0, o[dt]);
      o[dt] = MFMA16(pf1, vf1, o[dt]);
    }
    __builtin_amdgcn_s_setprio(0);

    __syncthreads();
    if (more) WRITETILE();
    __syncthreads();
  }

  if (!partial) {
    const float inv = 1.0f / lrun;
    float iv[4];
#pragma unroll
    for (int r = 0; r < 4; ++r) iv[r] = __shfl(inv, g4 + r, 64);
#pragma unroll
    for (int r = 0; r < 4; ++r) {
      const int qrow = q0 + wave * 16 + g4 + r;
#pragma unroll
      for (int dt = 0; dt < 8; ++dt)
        op[baseo + (size_t)qrow * DMODEL + dt * 16 + fr] = f2bf(o[dt][r] * iv[r]);
    }
  } else {
    const int sidx = (((b * 8 + (h >> 1)) * 16 + (qt - 16)) << 1) + part;
    const size_t sb = (size_t)sidx * 64;
#pragma unroll
    for (int r = 0; r < 4; ++r) {
      const size_t row = sb + wave * 16 + g4 + r;
#pragma unroll
      for (int dt = 0; dt < 8; ++dt)
        pO[row * HDIM + dt * 16 + fr] = f2bf(o[dt][r]);
    }
    if (lane < 16) {
      pm[sb + wave * 16 + lane] = mrun;
      pl[sb + wave * 16 + lane] = lrun;
    }
  }
}

// ---------------------------------------------------------------------------
// Merge two partials per (b, even h, qt>=16). Grid 256 blocks x 256 thr.
// ---------------------------------------------------------------------------
__global__ __launch_bounds__(256) void merge_kernel(const u16* __restrict__ pO,
                                                    const float* __restrict__ pm,
                                                    const float* __restrict__ pl,
                                                    u16* __restrict__ op) {
  const int x = blockIdx.x;            // 0..255 = (b*8+eh)*16 + qt16
  const int qt16 = x & 15, eh = (x >> 4) & 7, b = x >> 7;
  const int h = eh * 2, qt = 16 + qt16;
  const int s0 = x * 2, s1 = s0 + 1;

  for (int i = 0; i < 4; ++i) {
    const int vidx = threadIdx.x + i * 256;  // 0..1023
    const int row = vidx >> 4, d8 = (vidx & 15) * 8;
    const float m0 = pm[s0 * 64 + row], m1 = pm[s1 * 64 + row];
    const float l0 = pl[s0 * 64 + row], l1 = pl[s1 * 64 + row];
    const float m = fmaxf(m0, m1);
    const float w0 = __expf((m0 - m) * SC), w1 = __expf((m1 - m) * SC);
    const float inv = 1.0f / (l0 * w0 + l1 * w1);
    bf16x8 a = *(const bf16x8*)&pO[((size_t)s0 * 64 + row) * HDIM + d8];
    bf16x8 c = *(const bf16x8*)&pO[((size_t)s1 * 64 + row) * HDIM + d8];
    bf16x8 r;
#pragma unroll
    for (int j = 0; j < 8; ++j)
      r[j] = (short)f2bf((bf2f((u16)a[j]) * w0 + bf2f((u16)c[j]) * w1) * inv);
    *(bf16x8*)&op[((size_t)(b * T_SEQ + qt * 64 + row)) * DMODEL + h * HDIM + d8] = r;
  }
}

// ---------------------------------------------------------------------------
extern "C" void kernel_launch(void* const* d_in, const int* in_sizes, int n_in,
                              void* d_out, int out_size, void* d_ws, size_t ws_size,
                              hipStream_t stream) {
  (void)in_sizes; (void)n_in; (void)out_size; (void)ws_size;
  const float* x  = (const float*)d_in[0];
  const float* Wq = (const float*)d_in[1];
  const float* Wk = (const float*)d_in[2];
  const float* Wv = (const float*)d_in[3];
  const float* Wo = (const float*)d_in[4];

  const size_t NX = (size_t)MROWS * DMODEL;
  const size_t NW = (size_t)DMODEL * DMODEL;
  u16* ws  = (u16*)d_ws;
  u16* xb  = ws;                 // bf16 x; later attention output
  u16* wqb = ws + NX;
  u16* wkb = wqb + NW;
  u16* wvb = wkb + NW;
  u16* wob = wvb + NW;
  u16* qkb = wob + NW;                          // [4096][4096]
  u16* vtb = qkb + (size_t)MROWS * 2 * DMODEL;  // [32][128][2048]

  // partial buffers reuse dead wq/wk/wv region after QKV GEMM (8.9 MB < 25 MB)
  u16*   pO = wqb;                               // [512][64][128] bf16
  float* pm = (float*)(wqb + (size_t)512 * 64 * HDIM);
  float* pl = pm + 512 * 64;

  convert_all<<<2048, 256, 0, stream>>>(x, Wq, Wk, Wv, Wo, ws);

  gemm_fast<0><<<dim3(3 * DMODEL / BN, MROWS / BM), 256, 0, stream>>>(
      xb, wqb, wkb, wvb, qkb, vtb, nullptr, DMODEL);

  attn_kernel<<<dim3(48, NHEADS, 2), 256, 0, stream>>>(qkb, vtb, xb, pO, pm, pl);

  merge_kernel<<<256, 256, 0, stream>>>(pO, pm, pl, xb);

  gemm_fast<1><<<dim3(DMODEL / BN, MROWS / BM), 256, 0, stream>>>(
      xb, wob, nullptr, nullptr, nullptr, nullptr, (float*)d_out, DMODEL);
}

// Round 4
// 319.799 us; speedup vs baseline: 1.9099x; 1.0079x over previous
//
#include <hip/hip_runtime.h>

typedef __attribute__((ext_vector_type(4))) float f32x4;
typedef __attribute__((ext_vector_type(8))) short bf16x8;
typedef __attribute__((ext_vector_type(4))) unsigned short u16x4;
typedef unsigned short u16;

#define MFMA16(a, b, c) __builtin_amdgcn_mfma_f32_16x16x32_bf16((a), (b), (c), 0, 0, 0)

#define T_SEQ 2048
#define DMODEL 2048
#define NHEADS 16
#define HDIM 128
#define WINDOW 256
#define MROWS 4096  // B*T
#define SC 0.08838834764831845f  // 1/sqrt(128)

__device__ __forceinline__ u16 f2bf(float f) {
  union { float f; unsigned u; } v; v.f = f;
  return (u16)((v.u + 0x7FFFu + ((v.u >> 16) & 1u)) >> 16);
}
__device__ __forceinline__ float bf2f(u16 u) {
  union { unsigned u; float f; } v; v.u = ((unsigned)u) << 16;
  return v.f;
}
__device__ __forceinline__ void gl_lds16(const u16* g, u16* l) {
  __builtin_amdgcn_global_load_lds((const __attribute__((address_space(1))) void*)(g),
                                   (__attribute__((address_space(3))) void*)(l), 16, 0, 0);
}

// ---------------------------------------------------------------------------
// Convert x, Wq, Wk, Wv, Wo (f32) -> contiguous bf16: [xb NX][wq][wk][wv][wo]
// ---------------------------------------------------------------------------
__global__ __launch_bounds__(256) void convert_all(const float* __restrict__ x,
                                                   const float* __restrict__ wq,
                                                   const float* __restrict__ wk,
                                                   const float* __restrict__ wv,
                                                   const float* __restrict__ wo,
                                                   u16* __restrict__ dst) {
  const size_t NX = (size_t)MROWS * DMODEL;
  const size_t NW = (size_t)DMODEL * DMODEL;
  const size_t chunks = (NX + 4 * NW) / 8;
  for (size_t ci = (size_t)blockIdx.x * 256 + threadIdx.x; ci < chunks;
       ci += (size_t)gridDim.x * 256) {
    const size_t off = ci * 8;
    const float* src;
    size_t so;
    if (off < NX) { src = x; so = off; }
    else {
      size_t rem = off - NX;
      if (rem < NW) { src = wq; so = rem; }
      else if (rem < 2 * NW) { src = wk; so = rem - NW; }
      else if (rem < 3 * NW) { src = wv; so = rem - 2 * NW; }
      else { src = wo; so = rem - 3 * NW; }
    }
    f32x4 a = *(const f32x4*)&src[so];
    f32x4 b = *(const f32x4*)&src[so + 4];
    bf16x8 o;
#pragma unroll
    for (int j = 0; j < 4; ++j) { o[j] = (short)f2bf(a[j]); o[j + 4] = (short)f2bf(b[j]); }
    *(bf16x8*)&dst[off] = o;
  }
}

// ---------------------------------------------------------------------------
// Deep-pipelined QKV GEMM: C[4096,6144] = A @ [Wq|Wk|Wv]^T, all bf16.
// 256x256 tile, BK=32, 512 thr = 8 waves (2m x 4n), per-wave 128x64 (8x4 frags).
// LDS 64 KB: A[2][256][32] + B[2][256][32], XOR-chunk swizzle both sides.
// 2 phases per K-tile, counted vmcnt(2) once per tile (T3+T4), setprio (T5).
// Epilogue: q,k cols -> qk buffer; v cols -> transposed vt buffer.
// ---------------------------------------------------------------------------
__global__ __launch_bounds__(512, 2) void gemm_qkv(const u16* __restrict__ A,
                                                   const u16* __restrict__ W0,
                                                   const u16* __restrict__ W1,
                                                   const u16* __restrict__ W2,
                                                   u16* __restrict__ qk,
                                                   u16* __restrict__ vt) {
  __shared__ u16 lds[32768];  // 64 KB
  const int tid = threadIdx.x, w = tid >> 6, lane = tid & 63;
  const int wm = w >> 2, wn = w & 3;
  const int fr = lane & 15, g4 = (lane >> 4) * 4;
  const int swz = (((lane >> 4) ^ (fr & 3)) << 3);  // swizzled chunk u16-offset

  // XCD-aware bijective swizzle (384 blocks, 384%8==0, cpx=48)
  int flat = blockIdx.x;
  flat = (flat & 7) * 48 + (flat >> 3);
  const int mt = flat / 24, nt = flat - mt * 24;
  const int m0 = mt * 256, n0 = nt * 256;
  const int wsel = n0 >> 11;
  const u16* Bw = (wsel == 0) ? W0 : ((wsel == 1) ? W1 : W2);
  const int nloc = n0 & 2047;

  // staging constants: thread covers chunk q of each 128-row half (512 chunks)
  const int q = (w << 6) + lane;             // 0..511
  const int sr = q >> 2;                     // row within half 0..127
  const int sc = (((q & 3) ^ (sr & 3)) << 3);  // inverse-swizzled source chunk
  const u16* srcA = A + (size_t)(m0 + sr) * DMODEL + sc;
  const u16* srcB = Bw + (size_t)(nloc + sr) * DMODEL + sc;
  u16* dA = lds + (w << 9);           // wave-uniform dest (lane*16B implicit)
  u16* dB = lds + 16384 + (w << 9);
  const int rowA = (wm << 7) + fr;
  const int rowB = (wn << 6) + fr;

#define SA(buf, half, kt) gl_lds16(srcA + (size_t)(half) * 128 * DMODEL + (kt) * 32, dA + (buf) * 8192 + (half) * 4096)
#define SB(buf, half, kt) gl_lds16(srcB + (size_t)(half) * 128 * DMODEL + (kt) * 32, dB + (buf) * 8192 + (half) * 4096)

  f32x4 acc[8][4];
#pragma unroll
  for (int i = 0; i < 8; ++i)
#pragma unroll
    for (int j = 0; j < 4; ++j) acc[i][j] = (f32x4){0.f, 0.f, 0.f, 0.f};

  // prologue: A(0), B(0), B(1)
  SA(0, 0, 0); SA(0, 1, 0);
  SB(0, 0, 0); SB(0, 1, 0);
  SB(1, 0, 1); SB(1, 1, 1);
  asm volatile("s_waitcnt vmcnt(2)" ::: "memory");  // A(0),B(0) done; B(1) in flight
  __builtin_amdgcn_s_barrier();

  const int NT = DMODEL / 32;  // 64
  for (int t = 0; t < NT; ++t) {
    const int c = t & 1;
    const u16* Ac = lds + c * 8192;
    const u16* Bc = lds + 16384 + c * 8192;
    // ---- P0: reads + A(t+1) stage, 16 MFMA (mi 0-3) ----
    bf16x8 a[4], b[4];
#pragma unroll
    for (int mi = 0; mi < 4; ++mi) a[mi] = *(const bf16x8*)&Ac[(rowA + mi * 16) * 32 + swz];
#pragma unroll
    for (int ni = 0; ni < 4; ++ni) b[ni] = *(const bf16x8*)&Bc[(rowB + ni * 16) * 32 + swz];
    if (t + 1 < NT) { SA(c ^ 1, 0, t + 1); SA(c ^ 1, 1, t + 1); }
    asm volatile("" ::: "memory");
    __builtin_amdgcn_s_barrier();
    __builtin_amdgcn_s_setprio(1);
#pragma unroll
    for (int mi = 0; mi < 4; ++mi)
#pragma unroll
      for (int ni = 0; ni < 4; ++ni) acc[mi][ni] = MFMA16(a[mi], b[ni], acc[mi][ni]);
    __builtin_amdgcn_s_setprio(0);
    asm volatile("" ::: "memory");
    __builtin_amdgcn_s_barrier();
    // ---- P1: reads (mi 4-7) + B(t+2) stage, vmcnt, 16 MFMA ----
    bf16x8 a2[4];
#pragma unroll
    for (int mi = 0; mi < 4; ++mi)
      a2[mi] = *(const bf16x8*)&Ac[(rowA + 64 + mi * 16) * 32 + swz];
    if (t + 2 < NT) {
      SB(c, 0, t + 2); SB(c, 1, t + 2);
      asm volatile("s_waitcnt vmcnt(2)" ::: "memory");  // A(t+1) forced complete
    } else {
      asm volatile("s_waitcnt vmcnt(0)" ::: "memory");
    }
    __builtin_amdgcn_s_barrier();
    __builtin_amdgcn_s_setprio(1);
#pragma unroll
    for (int mi = 0; mi < 4; ++mi)
#pragma unroll
      for (int ni = 0; ni < 4; ++ni) acc[mi + 4][ni] = MFMA16(a2[mi], b[ni], acc[mi + 4][ni]);
    __builtin_amdgcn_s_setprio(0);
    asm volatile("" ::: "memory");
    __builtin_amdgcn_s_barrier();
  }

  // epilogue
#pragma unroll
  for (int mi = 0; mi < 8; ++mi)
#pragma unroll
    for (int ni = 0; ni < 4; ++ni) {
      const int row0 = m0 + wm * 128 + mi * 16 + g4;
      const int cg = n0 + wn * 64 + ni * 16 + fr;
      if (cg < 2 * DMODEL) {
#pragma unroll
        for (int r = 0; r < 4; ++r)
          qk[(size_t)(row0 + r) * (2 * DMODEL) + cg] = f2bf(acc[mi][ni][r]);
      } else {
        const int cc = cg - 2 * DMODEL;
        const int hh = cc >> 7, d = cc & 127;
        const int bb = row0 >> 11, tl = row0 & 2047;
        u16x4 w4;
#pragma unroll
        for (int r = 0; r < 4; ++r) w4[r] = f2bf(acc[mi][ni][r]);
        *(u16x4*)&vt[((size_t)(bb * NHEADS + hh) * HDIM + d) * T_SEQ + tl] = w4;
      }
    }
#undef SA
#undef SB
}

// ---------------------------------------------------------------------------
// m97-structure GEMM (kept for out-projection). C = A @ W^T, f32 out.
// ---------------------------------------------------------------------------
#define BM 128
#define BN 128
#define BK 32

__global__ __launch_bounds__(256) void gemm_out(const u16* __restrict__ A,
                                                const u16* __restrict__ W0,
                                                float* __restrict__ outf,
                                                int K) {
  __shared__ u16 As[BM * BK];
  __shared__ u16 Bs[BN * BK];
  const int tid = threadIdx.x, wave = tid >> 6, lane = tid & 63;
  const int fr = lane & 15, ko = (lane >> 4) * 8;
  const int wm = (wave >> 1) * 64, wn = (wave & 1) * 64;

  int flat = blockIdx.y * gridDim.x + blockIdx.x;
  const int nwg = gridDim.x * gridDim.y;
  const int cpx = nwg >> 3;
  flat = (flat & 7) * cpx + (flat >> 3);
  const int m0 = (flat / gridDim.x) * BM;
  const int n0 = (flat % gridDim.x) * BN;

  const int srow = tid >> 2;
  const int scol = (tid & 3) * 8;

  f32x4 acc[4][4];
#pragma unroll
  for (int i = 0; i < 4; ++i)
#pragma unroll
    for (int j = 0; j < 4; ++j) acc[i][j] = (f32x4){0.f, 0.f, 0.f, 0.f};

  for (int k0 = 0; k0 < K; k0 += BK) {
#pragma unroll
    for (int i = 0; i < 2; ++i) {
      const int row = srow + i * 64;
      gl_lds16(&A[(size_t)(m0 + row) * K + k0 + scol], &As[(i * 256 + wave * 64) * 8]);
      gl_lds16(&W0[(size_t)(n0 + row) * K + k0 + scol], &Bs[(i * 256 + wave * 64) * 8]);
    }
    __syncthreads();
    bf16x8 af[4], bfr[4];
#pragma unroll
    for (int i = 0; i < 4; ++i) af[i] = *(const bf16x8*)&As[(wm + i * 16 + fr) * BK + ko];
#pragma unroll
    for (int i = 0; i < 4; ++i) bfr[i] = *(const bf16x8*)&Bs[(wn + i * 16 + fr) * BK + ko];
#pragma unroll
    for (int mi = 0; mi < 4; ++mi)
#pragma unroll
      for (int ni = 0; ni < 4; ++ni)
        acc[mi][ni] = MFMA16(af[mi], bfr[ni], acc[mi][ni]);
    __syncthreads();
  }

#pragma unroll
  for (int mi = 0; mi < 4; ++mi)
#pragma unroll
    for (int ni = 0; ni < 4; ++ni) {
      const int row0 = m0 + wm + mi * 16 + (lane >> 4) * 4;
      const int c = n0 + wn + ni * 16 + fr;
#pragma unroll
      for (int r = 0; r < 4; ++r)
        outf[(size_t)(row0 + r) * DMODEL + c] = acc[mi][ni][r];
    }
}

// ---------------------------------------------------------------------------
// Striped flash attention (unchanged from round 3, known-good).
// ---------------------------------------------------------------------------
#define QB 64
#define KVB 64
#define LDK 136
#define LDV 72
#define LDP 80

__global__ __launch_bounds__(256) void attn_kernel(const u16* __restrict__ qk,
                                                   const u16* __restrict__ vt,
                                                   u16* __restrict__ op,
                                                   u16* __restrict__ pO,
                                                   float* __restrict__ pm,
                                                   float* __restrict__ pl) {
  __shared__ u16 Ks[KVB][LDK];
  __shared__ u16 Vs[HDIM][LDV];
  __shared__ u16 Ps[4][16][LDP];

  const int bx = blockIdx.x, h = blockIdx.y, b = blockIdx.z;
  const bool isglobal = (h & 1) == 0;
  int qt, klo, khi, part = 0;
  bool partial = false;
  if (isglobal) {
    const int c = 47 - bx;
    if (c < 16) { qt = c; klo = 0; khi = qt; }
    else {
      qt = 16 + ((c - 16) >> 1);
      part = (c - 16) & 1;
      partial = true;
      if (part == 0) { klo = 0; khi = 15; } else { klo = 16; khi = qt; }
    }
  } else {
    if (bx >= 32) return;
    qt = 31 - bx;
    const int lo_ = qt * QB - (WINDOW - 1);
    klo = lo_ > 0 ? (lo_ >> 6) : 0;
    khi = qt;
  }

  const int tid = threadIdx.x, wave = tid >> 6, lane = tid & 63;
  const int fr = lane & 15, ko = (lane >> 4) * 8, g4 = (lane >> 4) * 4;
  const int q0 = qt * QB;
  const size_t baseq = (size_t)b * T_SEQ * (2 * DMODEL) + (size_t)h * HDIM;
  const size_t basek = baseq + DMODEL;
  const size_t basev = (size_t)(b * NHEADS + h) * HDIM * T_SEQ;
  const size_t baseo = (size_t)b * T_SEQ * DMODEL + (size_t)h * HDIM;

  bf16x8 qf[4];
  {
    const int qrow = q0 + wave * 16 + fr;
#pragma unroll
    for (int ds = 0; ds < 4; ++ds)
      qf[ds] = *(const bf16x8*)&qk[baseq + (size_t)qrow * (2 * DMODEL) + ds * 32 + ko];
  }

  float mrun = -1e30f, lrun = 0.f;
  f32x4 o[8];
#pragma unroll
  for (int dt = 0; dt < 8; ++dt) o[dt] = (f32x4){0.f, 0.f, 0.f, 0.f};

  const int kr = tid >> 4, kc = (tid & 15) * 8;
  const int vr = tid >> 3, vc = (tid & 7) * 8;
  bf16x8 kreg[4], vreg[4];

#define LOADTILE(KT)                                                                      \
  {                                                                                       \
    _Pragma("unroll") for (int it = 0; it < 4; ++it) {                                    \
      kreg[it] = *(const bf16x8*)&qk[basek + (size_t)((KT) * KVB + kr + it * 16) * (2 * DMODEL) + kc]; \
      vreg[it] = *(const bf16x8*)&vt[basev + (size_t)(vr + it * 32) * T_SEQ + (KT) * KVB + vc];        \
    }                                                                                     \
  }
#define WRITETILE()                                                                       \
  {                                                                                       \
    _Pragma("unroll") for (int it = 0; it < 4; ++it) {                                    \
      *(bf16x8*)&Ks[kr + it * 16][kc] = kreg[it];                                         \
      *(bf16x8*)&Vs[vr + it * 32][vc] = vreg[it];                                         \
    }                                                                                     \
  }

  LOADTILE(klo);
  WRITETILE();
  __syncthreads();

  const int qg = q0 + wave * 16 + fr;

  for (int kt = klo; kt <= khi; ++kt) {
    const bool more = kt < khi;
    if (more) LOADTILE(kt + 1);

    f32x4 s[4];
    __builtin_amdgcn_s_setprio(1);
#pragma unroll
    for (int kk = 0; kk < 4; ++kk) {
      f32x4 a = (f32x4){0.f, 0.f, 0.f, 0.f};
#pragma unroll
      for (int ds = 0; ds < 4; ++ds) {
        bf16x8 kf = *(const bf16x8*)&Ks[kk * 16 + fr][ds * 32 + ko];
        a = MFMA16(kf, qf[ds], a);
      }
      s[kk] = a;
    }
    __builtin_amdgcn_s_setprio(0);

    float sv[16];
    float pmax = -1e30f;
#pragma unroll
    for (int kk = 0; kk < 4; ++kk)
#pragma unroll
      for (int reg = 0; reg < 4; ++reg) {
        const int cg = kt * KVB + kk * 16 + g4 + reg;
        const bool allowed = (cg <= qg) && (isglobal || cg >= qg - (WINDOW - 1));
        const float v = allowed ? s[kk][reg] : -1e30f;
        sv[kk * 4 + reg] = v;
        pmax = fmaxf(pmax, v);
      }
    pmax = fmaxf(pmax, __shfl_xor(pmax, 16, 64));
    pmax = fmaxf(pmax, __shfl_xor(pmax, 32, 64));
    const float nm = fmaxf(mrun, pmax);
    const float fac = __expf((mrun - nm) * SC);
    mrun = nm;
    float rs = 0.f;
    u16 pb[16];
#pragma unroll
    for (int i = 0; i < 16; ++i) {
      const float p = (sv[i] > -5e29f) ? __expf((sv[i] - nm) * SC) : 0.f;
      rs += p;
      pb[i] = f2bf(p);
    }
    rs += __shfl_xor(rs, 16, 64);
    rs += __shfl_xor(rs, 32, 64);
    lrun = lrun * fac + rs;

#pragma unroll
    for (int kk = 0; kk < 4; ++kk) {
      u16x4 w;
      w[0] = pb[kk * 4]; w[1] = pb[kk * 4 + 1]; w[2] = pb[kk * 4 + 2]; w[3] = pb[kk * 4 + 3];
      *(u16x4*)&Ps[wave][fr][kk * 16 + g4] = w;
    }

    float ff[4];
#pragma unroll
    for (int r = 0; r < 4; ++r) ff[r] = __shfl(fac, g4 + r, 64);
#pragma unroll
    for (int dt = 0; dt < 8; ++dt)
#pragma unroll
      for (int r = 0; r < 4; ++r) o[dt][r] *= ff[r];

    bf16x8 pf0 = *(const bf16x8*)&Ps[wave][fr][ko];
    bf16x8 pf1 = *(const bf16x8*)&Ps[wave][fr][32 + ko];
    __builtin_amdgcn_s_setprio(1);
#pragma unroll
    for (int dt = 0; dt < 8; ++dt) {
      bf16x8 vf0 = *(const bf16x8*)&Vs[dt * 16 + fr][ko];
      bf16x8 vf1 = *(const bf16x8*)&Vs[dt * 16 + fr][32 + ko];
      o[dt] = MFMA16(pf0, vf0, o[dt]);
      o[dt] = MFMA16(pf1, vf1, o[dt]);
    }
    __builtin_amdgcn_s_setprio(0);

    __syncthreads();
    if (more) WRITETILE();
    __syncthreads();
  }

  if (!partial) {
    const float inv = 1.0f / lrun;
    float iv[4];
#pragma unroll
    for (int r = 0; r < 4; ++r) iv[r] = __shfl(inv, g4 + r, 64);
#pragma unroll
    for (int r = 0; r < 4; ++r) {
      const int qrow = q0 + wave * 16 + g4 + r;
#pragma unroll
      for (int dt = 0; dt < 8; ++dt)
        op[baseo + (size_t)qrow * DMODEL + dt * 16 + fr] = f2bf(o[dt][r] * iv[r]);
    }
  } else {
    const int sidx = (((b * 8 + (h >> 1)) * 16 + (qt - 16)) << 1) + part;
    const size_t sb = (size_t)sidx * 64;
#pragma unroll
    for (int r = 0; r < 4; ++r) {
      const size_t row = sb + wave * 16 + g4 + r;
#pragma unroll
      for (int dt = 0; dt < 8; ++dt)
        pO[row * HDIM + dt * 16 + fr] = f2bf(o[dt][r]);
    }
    if (lane < 16) {
      pm[sb + wave * 16 + lane] = mrun;
      pl[sb + wave * 16 + lane] = lrun;
    }
  }
}

// ---------------------------------------------------------------------------
// Merge two partials per (b, even h, qt>=16). Grid 256 blocks x 256 thr.
// ---------------------------------------------------------------------------
__global__ __launch_bounds__(256) void merge_kernel(const u16* __restrict__ pO,
                                                    const float* __restrict__ pm,
                                                    const float* __restrict__ pl,
                                                    u16* __restrict__ op) {
  const int x = blockIdx.x;
  const int qt16 = x & 15, eh = (x >> 4) & 7, b = x >> 7;
  const int h = eh * 2, qt = 16 + qt16;
  const int s0 = x * 2, s1 = s0 + 1;

  for (int i = 0; i < 4; ++i) {
    const int vidx = threadIdx.x + i * 256;
    const int row = vidx >> 4, d8 = (vidx & 15) * 8;
    const float m0 = pm[s0 * 64 + row], m1 = pm[s1 * 64 + row];
    const float l0 = pl[s0 * 64 + row], l1 = pl[s1 * 64 + row];
    const float m = fmaxf(m0, m1);
    const float w0 = __expf((m0 - m) * SC), w1 = __expf((m1 - m) * SC);
    const float inv = 1.0f / (l0 * w0 + l1 * w1);
    bf16x8 a = *(const bf16x8*)&pO[((size_t)s0 * 64 + row) * HDIM + d8];
    bf16x8 c = *(const bf16x8*)&pO[((size_t)s1 * 64 + row) * HDIM + d8];
    bf16x8 r;
#pragma unroll
    for (int j = 0; j < 8; ++j)
      r[j] = (short)f2bf((bf2f((u16)a[j]) * w0 + bf2f((u16)c[j]) * w1) * inv);
    *(bf16x8*)&op[((size_t)(b * T_SEQ + qt * 64 + row)) * DMODEL + h * HDIM + d8] = r;
  }
}

// ---------------------------------------------------------------------------
extern "C" void kernel_launch(void* const* d_in, const int* in_sizes, int n_in,
                              void* d_out, int out_size, void* d_ws, size_t ws_size,
                              hipStream_t stream) {
  (void)in_sizes; (void)n_in; (void)out_size; (void)ws_size;
  const float* x  = (const float*)d_in[0];
  const float* Wq = (const float*)d_in[1];
  const float* Wk = (const float*)d_in[2];
  const float* Wv = (const float*)d_in[3];
  const float* Wo = (const float*)d_in[4];

  const size_t NX = (size_t)MROWS * DMODEL;
  const size_t NW = (size_t)DMODEL * DMODEL;
  u16* ws  = (u16*)d_ws;
  u16* xb  = ws;                 // bf16 x; later attention output
  u16* wqb = ws + NX;
  u16* wkb = wqb + NW;
  u16* wvb = wkb + NW;
  u16* wob = wvb + NW;
  u16* qkb = wob + NW;                          // [4096][4096]
  u16* vtb = qkb + (size_t)MROWS * 2 * DMODEL;  // [32][128][2048]

  u16*   pO = wqb;                               // partials reuse dead wq/wk region
  float* pm = (float*)(wqb + (size_t)512 * 64 * HDIM);
  float* pl = pm + 512 * 64;

  convert_all<<<2048, 256, 0, stream>>>(x, Wq, Wk, Wv, Wo, ws);

  gemm_qkv<<<384, 512, 0, stream>>>(xb, wqb, wkb, wvb, qkb, vtb);

  attn_kernel<<<dim3(48, NHEADS, 2), 256, 0, stream>>>(qkb, vtb, xb, pO, pm, pl);

  merge_kernel<<<256, 256, 0, stream>>>(pO, pm, pl, xb);

  gemm_out<<<dim3(DMODEL / BN, MROWS / BM), 256, 0, stream>>>(
      xb, wob, (float*)d_out, DMODEL);
}

// Round 5
// 277.359 us; speedup vs baseline: 2.2021x; 1.1530x over previous
//
#include <hip/hip_runtime.h>

typedef __attribute__((ext_vector_type(4))) float f32x4;
typedef __attribute__((ext_vector_type(8))) short bf16x8;
typedef __attribute__((ext_vector_type(4))) unsigned short u16x4;
typedef unsigned short u16;

#define MFMA16(a, b, c) __builtin_amdgcn_mfma_f32_16x16x32_bf16((a), (b), (c), 0, 0, 0)

#define T_SEQ 2048
#define DMODEL 2048
#define NHEADS 16
#define HDIM 128
#define WINDOW 256
#define MROWS 4096  // B*T
#define SC 0.08838834764831845f  // 1/sqrt(128)

__device__ __forceinline__ u16 f2bf(float f) {
  union { float f; unsigned u; } v; v.f = f;
  return (u16)((v.u + 0x7FFFu + ((v.u >> 16) & 1u)) >> 16);
}
__device__ __forceinline__ float bf2f(u16 u) {
  union { unsigned u; float f; } v; v.u = ((unsigned)u) << 16;
  return v.f;
}
__device__ __forceinline__ void gl_lds16(const u16* g, u16* l) {
  __builtin_amdgcn_global_load_lds((const __attribute__((address_space(1))) void*)(g),
                                   (__attribute__((address_space(3))) void*)(l), 16, 0, 0);
}

// ---------------------------------------------------------------------------
// Convert x, Wq, Wk, Wv, Wo (f32) -> contiguous bf16: [xb NX][wq][wk][wv][wo]
// ---------------------------------------------------------------------------
__global__ __launch_bounds__(256) void convert_all(const float* __restrict__ x,
                                                   const float* __restrict__ wq,
                                                   const float* __restrict__ wk,
                                                   const float* __restrict__ wv,
                                                   const float* __restrict__ wo,
                                                   u16* __restrict__ dst) {
  const size_t NX = (size_t)MROWS * DMODEL;
  const size_t NW = (size_t)DMODEL * DMODEL;
  const size_t chunks = (NX + 4 * NW) / 8;
  for (size_t ci = (size_t)blockIdx.x * 256 + threadIdx.x; ci < chunks;
       ci += (size_t)gridDim.x * 256) {
    const size_t off = ci * 8;
    const float* src;
    size_t so;
    if (off < NX) { src = x; so = off; }
    else {
      size_t rem = off - NX;
      if (rem < NW) { src = wq; so = rem; }
      else if (rem < 2 * NW) { src = wk; so = rem - NW; }
      else if (rem < 3 * NW) { src = wv; so = rem - 2 * NW; }
      else { src = wo; so = rem - 3 * NW; }
    }
    f32x4 a = *(const f32x4*)&src[so];
    f32x4 b = *(const f32x4*)&src[so + 4];
    bf16x8 o;
#pragma unroll
    for (int j = 0; j < 4; ++j) { o[j] = (short)f2bf(a[j]); o[j + 4] = (short)f2bf(b[j]); }
    *(bf16x8*)&dst[off] = o;
  }
}

// ---------------------------------------------------------------------------
// 4-phase pipelined QKV GEMM: C[4096,6144] = A @ Wcat^T, all bf16.
// BM=256, BN=192, BK=64. Grid 512 blocks (16 mt x 32 nt) = 2 balanced rounds,
// 1 block/CU. 512 thr = 8 waves (2m x 4n); per-wave 128x48 (8mi x 3ni frags).
// LDS 112 KB: A[2][256][64] + B[2][192][64], XOR slot-swizzle (c ^= row&7)
// realized via pre-swizzled gl_lds source + swizzled ds_read (rule 21).
// Per K-step: 4 phases x {reads | stage(next tile -> other buf) | barrier |
// 12 MFMA (setprio) | barrier}; vmcnt(0) once per step on >=2-phase-old loads.
// Epilogue: q,k cols -> qk buffer; v cols -> transposed vt buffer.
// ---------------------------------------------------------------------------
#define QKV_NT 32  // K / 64

__global__ __launch_bounds__(512, 2) void gemm_qkv(const u16* __restrict__ A,
                                                   const u16* __restrict__ W,
                                                   u16* __restrict__ qk,
                                                   u16* __restrict__ vt) {
  __shared__ u16 lds[57344];  // A: [0,32768) two bufs of 16384; B: [32768,57344) two bufs of 12288
  const int tid = threadIdx.x, w = tid >> 6, lane = tid & 63;
  const int wm = w >> 2, wn = w & 3;
  const int fr = lane & 15, g = lane >> 4, g4 = g * 4;

  // XCD-aware decomposition: xcd gets contiguous 4-nt slice x all 16 mt
  const int xcd = blockIdx.x & 7, bi = blockIdx.x >> 3;
  const int mt = bi >> 2, nt = xcd * 4 + (bi & 3);
  const int m0 = mt * 256, n0 = nt * 192;

  // staging constants: lane l covers (row w*8 + (l>>3), slot l&7) of each 64-row
  // chunk; LDS slot p holds logical K-chunk c = p ^ (row&7) -> source chunk:
  const int rA = w * 8 + (lane >> 3);
  const int csrc = ((lane & 7) ^ (lane >> 3)) * 8;  // u16 offset of source chunk
  const u16* srcA = A + (size_t)(m0 + rA) * DMODEL + csrc;
  const u16* srcB = W + (size_t)(n0 + rA) * DMODEL + csrc;

#define SA(buf, CH, t) gl_lds16(srcA + (size_t)((CH) * 64) * DMODEL + (t) * 64, \
                                &lds[(buf) * 16384 + ((CH) * 64 + w * 8) * 64])
#define SB(buf, CH, t) gl_lds16(srcB + (size_t)((CH) * 64) * DMODEL + (t) * 64, \
                                &lds[32768 + (buf) * 12288 + ((CH) * 64 + w * 8) * 64])

  // frag-read swizzled chunk offsets (u16): chunk (kk*4+g) ^ (fr&7), x1 = x0^32
  const int x0 = ((g ^ (fr & 7))) * 8;
  const int x1 = x0 ^ 32;
  const int arow = wm * 128 + fr;  // + mi*16
  const int brow = wn * 48 + fr;   // + ni*16

  f32x4 acc[8][3];
#pragma unroll
  for (int i = 0; i < 8; ++i)
#pragma unroll
    for (int j = 0; j < 3; ++j) acc[i][j] = (f32x4){0.f, 0.f, 0.f, 0.f};

  // prologue: stage tile 0 into buf 0, drain, barrier
  SA(0, 0, 0); SA(0, 1, 0); SA(0, 2, 0); SA(0, 3, 0);
  SB(0, 0, 0); SB(0, 1, 0); SB(0, 2, 0);
  asm volatile("s_waitcnt vmcnt(0)" ::: "memory");
  __builtin_amdgcn_s_barrier();

  for (int t = 0; t < QKV_NT; ++t) {
    const int c = t & 1;
    const u16* Ab = lds + c * 16384;
    const u16* Bb = lds + 32768 + c * 12288;
    bf16x8 bfr[3][2];
#pragma unroll
    for (int p = 0; p < 4; ++p) {
      bf16x8 af[2][2];
#pragma unroll
      for (int m = 0; m < 2; ++m) {
        const int row = arow + (2 * p + m) * 16;
        af[m][0] = *(const bf16x8*)&Ab[row * 64 + x0];
        af[m][1] = *(const bf16x8*)&Ab[row * 64 + x1];
      }
      if (p == 0) {
#pragma unroll
        for (int ni = 0; ni < 3; ++ni) {
          const int row = brow + ni * 16;
          bfr[ni][0] = *(const bf16x8*)&Bb[row * 64 + x0];
          bfr[ni][1] = *(const bf16x8*)&Bb[row * 64 + x1];
        }
      }
      // stage next K-step's tile into the other buffer (issued early; waited
      // at end-of-step vmcnt(0) when >=2 phases old)
      if (t + 1 < QKV_NT) {
        if (p == 0) { SA(c ^ 1, 0, t + 1); SA(c ^ 1, 1, t + 1); SB(c ^ 1, 0, t + 1); SB(c ^ 1, 1, t + 1); }
        else if (p == 1) { SA(c ^ 1, 2, t + 1); SA(c ^ 1, 3, t + 1); SB(c ^ 1, 2, t + 1); }
      }
      __builtin_amdgcn_s_barrier();
      __builtin_amdgcn_s_setprio(1);
#pragma unroll
      for (int m = 0; m < 2; ++m)
#pragma unroll
        for (int ni = 0; ni < 3; ++ni) {
          acc[2 * p + m][ni] = MFMA16(af[m][0], bfr[ni][0], acc[2 * p + m][ni]);
          acc[2 * p + m][ni] = MFMA16(af[m][1], bfr[ni][1], acc[2 * p + m][ni]);
        }
      __builtin_amdgcn_s_setprio(0);
      if (p == 3) asm volatile("s_waitcnt vmcnt(0)" ::: "memory");
      __builtin_amdgcn_s_barrier();
    }
  }

  // epilogue: C row = base + g4 + reg, col = base + fr
#pragma unroll
  for (int mi = 0; mi < 8; ++mi)
#pragma unroll
    for (int ni = 0; ni < 3; ++ni) {
      const int row0 = m0 + wm * 128 + mi * 16 + g4;
      const int cg = n0 + wn * 48 + ni * 16 + fr;
      if (cg < 2 * DMODEL) {
#pragma unroll
        for (int r = 0; r < 4; ++r)
          qk[(size_t)(row0 + r) * (2 * DMODEL) + cg] = f2bf(acc[mi][ni][r]);
      } else {
        const int cc = cg - 2 * DMODEL;
        const int hh = cc >> 7, d = cc & 127;
        const int bb = row0 >> 11, tl = row0 & 2047;
        u16x4 w4;
#pragma unroll
        for (int r = 0; r < 4; ++r) w4[r] = f2bf(acc[mi][ni][r]);
        *(u16x4*)&vt[((size_t)(bb * NHEADS + hh) * HDIM + d) * T_SEQ + tl] = w4;
      }
    }
#undef SA
#undef SB
}

// ---------------------------------------------------------------------------
// m97-structure GEMM (out-projection, unchanged known-good). C = A @ W^T, f32.
// ---------------------------------------------------------------------------
#define BM 128
#define BN 128
#define BK 32

__global__ __launch_bounds__(256) void gemm_out(const u16* __restrict__ A,
                                                const u16* __restrict__ W0,
                                                float* __restrict__ outf,
                                                int K) {
  __shared__ u16 As[BM * BK];
  __shared__ u16 Bs[BN * BK];
  const int tid = threadIdx.x, wave = tid >> 6, lane = tid & 63;
  const int fr = lane & 15, ko = (lane >> 4) * 8;
  const int wm = (wave >> 1) * 64, wn = (wave & 1) * 64;

  int flat = blockIdx.y * gridDim.x + blockIdx.x;
  const int nwg = gridDim.x * gridDim.y;
  const int cpx = nwg >> 3;
  flat = (flat & 7) * cpx + (flat >> 3);
  const int m0 = (flat / gridDim.x) * BM;
  const int n0 = (flat % gridDim.x) * BN;

  const int srow = tid >> 2;
  const int scol = (tid & 3) * 8;

  f32x4 acc[4][4];
#pragma unroll
  for (int i = 0; i < 4; ++i)
#pragma unroll
    for (int j = 0; j < 4; ++j) acc[i][j] = (f32x4){0.f, 0.f, 0.f, 0.f};

  for (int k0 = 0; k0 < K; k0 += BK) {
#pragma unroll
    for (int i = 0; i < 2; ++i) {
      const int row = srow + i * 64;
      gl_lds16(&A[(size_t)(m0 + row) * K + k0 + scol], &As[(i * 256 + wave * 64) * 8]);
      gl_lds16(&W0[(size_t)(n0 + row) * K + k0 + scol], &Bs[(i * 256 + wave * 64) * 8]);
    }
    __syncthreads();
    bf16x8 af[4], bfr[4];
#pragma unroll
    for (int i = 0; i < 4; ++i) af[i] = *(const bf16x8*)&As[(wm + i * 16 + fr) * BK + ko];
#pragma unroll
    for (int i = 0; i < 4; ++i) bfr[i] = *(const bf16x8*)&Bs[(wn + i * 16 + fr) * BK + ko];
#pragma unroll
    for (int mi = 0; mi < 4; ++mi)
#pragma unroll
      for (int ni = 0; ni < 4; ++ni)
        acc[mi][ni] = MFMA16(af[mi], bfr[ni], acc[mi][ni]);
    __syncthreads();
  }

#pragma unroll
  for (int mi = 0; mi < 4; ++mi)
#pragma unroll
    for (int ni = 0; ni < 4; ++ni) {
      const int row0 = m0 + wm + mi * 16 + (lane >> 4) * 4;
      const int c = n0 + wn + ni * 16 + fr;
#pragma unroll
      for (int r = 0; r < 4; ++r)
        outf[(size_t)(row0 + r) * DMODEL + c] = acc[mi][ni][r];
    }
}

// ---------------------------------------------------------------------------
// Striped flash attention (unchanged, known-good).
// ---------------------------------------------------------------------------
#define QB 64
#define KVB 64
#define LDK 136
#define LDV 72
#define LDP 80

__global__ __launch_bounds__(256) void attn_kernel(const u16* __restrict__ qk,
                                                   const u16* __restrict__ vt,
                                                   u16* __restrict__ op,
                                                   u16* __restrict__ pO,
                                                   float* __restrict__ pm,
                                                   float* __restrict__ pl) {
  __shared__ u16 Ks[KVB][LDK];
  __shared__ u16 Vs[HDIM][LDV];
  __shared__ u16 Ps[4][16][LDP];

  const int bx = blockIdx.x, h = blockIdx.y, b = blockIdx.z;
  const bool isglobal = (h & 1) == 0;
  int qt, klo, khi, part = 0;
  bool partial = false;
  if (isglobal) {
    const int c = 47 - bx;
    if (c < 16) { qt = c; klo = 0; khi = qt; }
    else {
      qt = 16 + ((c - 16) >> 1);
      part = (c - 16) & 1;
      partial = true;
      if (part == 0) { klo = 0; khi = 15; } else { klo = 16; khi = qt; }
    }
  } else {
    if (bx >= 32) return;
    qt = 31 - bx;
    const int lo_ = qt * QB - (WINDOW - 1);
    klo = lo_ > 0 ? (lo_ >> 6) : 0;
    khi = qt;
  }

  const int tid = threadIdx.x, wave = tid >> 6, lane = tid & 63;
  const int fr = lane & 15, ko = (lane >> 4) * 8, g4 = (lane >> 4) * 4;
  const int q0 = qt * QB;
  const size_t baseq = (size_t)b * T_SEQ * (2 * DMODEL) + (size_t)h * HDIM;
  const size_t basek = baseq + DMODEL;
  const size_t basev = (size_t)(b * NHEADS + h) * HDIM * T_SEQ;
  const size_t baseo = (size_t)b * T_SEQ * DMODEL + (size_t)h * HDIM;

  bf16x8 qf[4];
  {
    const int qrow = q0 + wave * 16 + fr;
#pragma unroll
    for (int ds = 0; ds < 4; ++ds)
      qf[ds] = *(const bf16x8*)&qk[baseq + (size_t)qrow * (2 * DMODEL) + ds * 32 + ko];
  }

  float mrun = -1e30f, lrun = 0.f;
  f32x4 o[8];
#pragma unroll
  for (int dt = 0; dt < 8; ++dt) o[dt] = (f32x4){0.f, 0.f, 0.f, 0.f};

  const int kr = tid >> 4, kc = (tid & 15) * 8;
  const int vr = tid >> 3, vc = (tid & 7) * 8;
  bf16x8 kreg[4], vreg[4];

#define LOADTILE(KT)                                                                      \
  {                                                                                       \
    _Pragma("unroll") for (int it = 0; it < 4; ++it) {                                    \
      kreg[it] = *(const bf16x8*)&qk[basek + (size_t)((KT) * KVB + kr + it * 16) * (2 * DMODEL) + kc]; \
      vreg[it] = *(const bf16x8*)&vt[basev + (size_t)(vr + it * 32) * T_SEQ + (KT) * KVB + vc];        \
    }                                                                                     \
  }
#define WRITETILE()                                                                       \
  {                                                                                       \
    _Pragma("unroll") for (int it = 0; it < 4; ++it) {                                    \
      *(bf16x8*)&Ks[kr + it * 16][kc] = kreg[it];                                         \
      *(bf16x8*)&Vs[vr + it * 32][vc] = vreg[it];                                         \
    }                                                                                     \
  }

  LOADTILE(klo);
  WRITETILE();
  __syncthreads();

  const int qg = q0 + wave * 16 + fr;

  for (int kt = klo; kt <= khi; ++kt) {
    const bool more = kt < khi;
    if (more) LOADTILE(kt + 1);

    f32x4 s[4];
    __builtin_amdgcn_s_setprio(1);
#pragma unroll
    for (int kk = 0; kk < 4; ++kk) {
      f32x4 a = (f32x4){0.f, 0.f, 0.f, 0.f};
#pragma unroll
      for (int ds = 0; ds < 4; ++ds) {
        bf16x8 kf = *(const bf16x8*)&Ks[kk * 16 + fr][ds * 32 + ko];
        a = MFMA16(kf, qf[ds], a);
      }
      s[kk] = a;
    }
    __builtin_amdgcn_s_setprio(0);

    float sv[16];
    float pmax = -1e30f;
#pragma unroll
    for (int kk = 0; kk < 4; ++kk)
#pragma unroll
      for (int reg = 0; reg < 4; ++reg) {
        const int cg = kt * KVB + kk * 16 + g4 + reg;
        const bool allowed = (cg <= qg) && (isglobal || cg >= qg - (WINDOW - 1));
        const float v = allowed ? s[kk][reg] : -1e30f;
        sv[kk * 4 + reg] = v;
        pmax = fmaxf(pmax, v);
      }
    pmax = fmaxf(pmax, __shfl_xor(pmax, 16, 64));
    pmax = fmaxf(pmax, __shfl_xor(pmax, 32, 64));
    const float nm = fmaxf(mrun, pmax);
    const float fac = __expf((mrun - nm) * SC);
    mrun = nm;
    float rs = 0.f;
    u16 pb[16];
#pragma unroll
    for (int i = 0; i < 16; ++i) {
      const float p = (sv[i] > -5e29f) ? __expf((sv[i] - nm) * SC) : 0.f;
      rs += p;
      pb[i] = f2bf(p);
    }
    rs += __shfl_xor(rs, 16, 64);
    rs += __shfl_xor(rs, 32, 64);
    lrun = lrun * fac + rs;

#pragma unroll
    for (int kk = 0; kk < 4; ++kk) {
      u16x4 w;
      w[0] = pb[kk * 4]; w[1] = pb[kk * 4 + 1]; w[2] = pb[kk * 4 + 2]; w[3] = pb[kk * 4 + 3];
      *(u16x4*)&Ps[wave][fr][kk * 16 + g4] = w;
    }

    float ff[4];
#pragma unroll
    for (int r = 0; r < 4; ++r) ff[r] = __shfl(fac, g4 + r, 64);
#pragma unroll
    for (int dt = 0; dt < 8; ++dt)
#pragma unroll
      for (int r = 0; r < 4; ++r) o[dt][r] *= ff[r];

    bf16x8 pf0 = *(const bf16x8*)&Ps[wave][fr][ko];
    bf16x8 pf1 = *(const bf16x8*)&Ps[wave][fr][32 + ko];
    __builtin_amdgcn_s_setprio(1);
#pragma unroll
    for (int dt = 0; dt < 8; ++dt) {
      bf16x8 vf0 = *(const bf16x8*)&Vs[dt * 16 + fr][ko];
      bf16x8 vf1 = *(const bf16x8*)&Vs[dt * 16 + fr][32 + ko];
      o[dt] = MFMA16(pf0, vf0, o[dt]);
      o[dt] = MFMA16(pf1, vf1, o[dt]);
    }
    __builtin_amdgcn_s_setprio(0);

    __syncthreads();
    if (more) WRITETILE();
    __syncthreads();
  }

  if (!partial) {
    const float inv = 1.0f / lrun;
    float iv[4];
#pragma unroll
    for (int r = 0; r < 4; ++r) iv[r] = __shfl(inv, g4 + r, 64);
#pragma unroll
    for (int r = 0; r < 4; ++r) {
      const int qrow = q0 + wave * 16 + g4 + r;
#pragma unroll
      for (int dt = 0; dt < 8; ++dt)
        op[baseo + (size_t)qrow * DMODEL + dt * 16 + fr] = f2bf(o[dt][r] * iv[r]);
    }
  } else {
    const int sidx = (((b * 8 + (h >> 1)) * 16 + (qt - 16)) << 1) + part;
    const size_t sb = (size_t)sidx * 64;
#pragma unroll
    for (int r = 0; r < 4; ++r) {
      const size_t row = sb + wave * 16 + g4 + r;
#pragma unroll
      for (int dt = 0; dt < 8; ++dt)
        pO[row * HDIM + dt * 16 + fr] = f2bf(o[dt][r]);
    }
    if (lane < 16) {
      pm[sb + wave * 16 + lane] = mrun;
      pl[sb + wave * 16 + lane] = lrun;
    }
  }
}

// ---------------------------------------------------------------------------
// Merge two partials per (b, even h, qt>=16). Grid 256 blocks x 256 thr.
// ---------------------------------------------------------------------------
__global__ __launch_bounds__(256) void merge_kernel(const u16* __restrict__ pO,
                                                    const float* __restrict__ pm,
                                                    const float* __restrict__ pl,
                                                    u16* __restrict__ op) {
  const int x = blockIdx.x;
  const int qt16 = x & 15, eh = (x >> 4) & 7, b = x >> 7;
  const int h = eh * 2, qt = 16 + qt16;
  const int s0 = x * 2, s1 = s0 + 1;

  for (int i = 0; i < 4; ++i) {
    const int vidx = threadIdx.x + i * 256;
    const int row = vidx >> 4, d8 = (vidx & 15) * 8;
    const float m0 = pm[s0 * 64 + row], m1 = pm[s1 * 64 + row];
    const float l0 = pl[s0 * 64 + row], l1 = pl[s1 * 64 + row];
    const float m = fmaxf(m0, m1);
    const float w0 = __expf((m0 - m) * SC), w1 = __expf((m1 - m) * SC);
    const float inv = 1.0f / (l0 * w0 + l1 * w1);
    bf16x8 a = *(const bf16x8*)&pO[((size_t)s0 * 64 + row) * HDIM + d8];
    bf16x8 c = *(const bf16x8*)&pO[((size_t)s1 * 64 + row) * HDIM + d8];
    bf16x8 r;
#pragma unroll
    for (int j = 0; j < 8; ++j)
      r[j] = (short)f2bf((bf2f((u16)a[j]) * w0 + bf2f((u16)c[j]) * w1) * inv);
    *(bf16x8*)&op[((size_t)(b * T_SEQ + qt * 64 + row)) * DMODEL + h * HDIM + d8] = r;
  }
}

// ---------------------------------------------------------------------------
extern "C" void kernel_launch(void* const* d_in, const int* in_sizes, int n_in,
                              void* d_out, int out_size, void* d_ws, size_t ws_size,
                              hipStream_t stream) {
  (void)in_sizes; (void)n_in; (void)out_size; (void)ws_size;
  const float* x  = (const float*)d_in[0];
  const float* Wq = (const float*)d_in[1];
  const float* Wk = (const float*)d_in[2];
  const float* Wv = (const float*)d_in[3];
  const float* Wo = (const float*)d_in[4];

  const size_t NX = (size_t)MROWS * DMODEL;
  const size_t NW = (size_t)DMODEL * DMODEL;
  u16* ws  = (u16*)d_ws;
  u16* xb  = ws;                 // bf16 x; later attention output
  u16* wqb = ws + NX;            // [wq|wk|wv] contiguous = Wcat[6144][2048]
  u16* wkb = wqb + NW;
  u16* wvb = wkb + NW;
  u16* wob = wvb + NW;
  u16* qkb = wob + NW;                          // [4096][4096]
  u16* vtb = qkb + (size_t)MROWS * 2 * DMODEL;  // [32][128][2048]

  u16*   pO = wqb;                               // partials reuse dead wq/wk region
  float* pm = (float*)(wqb + (size_t)512 * 64 * HDIM);
  float* pl = pm + 512 * 64;

  convert_all<<<2048, 256, 0, stream>>>(x, Wq, Wk, Wv, Wo, ws);

  gemm_qkv<<<512, 512, 0, stream>>>(xb, wqb, qkb, vtb);

  attn_kernel<<<dim3(48, NHEADS, 2), 256, 0, stream>>>(qkb, vtb, xb, pO, pm, pl);

  merge_kernel<<<256, 256, 0, stream>>>(pO, pm, pl, xb);

  gemm_out<<<dim3(DMODEL / BN, MROWS / BM), 256, 0, stream>>>(
      xb, wob, (float*)d_out, DMODEL);
}